// Round 8
// baseline (46.176 us; speedup 1.0000x reference)
//
#include <hip/hip_runtime.h>

#define B_ 256
#define K_ 512
#define D_ 64
#define KD_ 576
#define LOG2E 1.44269504088896340736f

typedef float v2f __attribute__((ext_vector_type(2)));
typedef float v4f __attribute__((ext_vector_type(4)));
typedef short bf16x8 __attribute__((ext_vector_type(8)));
typedef float f32x16 __attribute__((ext_vector_type(16)));

#define ZERO16 {0.f,0.f,0.f,0.f,0.f,0.f,0.f,0.f,0.f,0.f,0.f,0.f,0.f,0.f,0.f,0.f}

__device__ __forceinline__ float fexp2(float x) {
#if __has_builtin(__builtin_amdgcn_exp2f)
    return __builtin_amdgcn_exp2f(x);
#else
    float r; asm("v_exp_f32 %0, %1" : "=v"(r) : "v"(x)); return r;
#endif
}
__device__ __forceinline__ float frcp(float x) {
#if __has_builtin(__builtin_amdgcn_rcpf)
    return __builtin_amdgcn_rcpf(x);
#else
    float r; asm("v_rcp_f32 %0, %1" : "=v"(r) : "v"(x)); return r;
#endif
}
__device__ __forceinline__ float fsig(float x) {
    return frcp(1.0f + fexp2(-LOG2E * x));
}
__device__ __forceinline__ ushort f2bf(float f) {
    union { float f; unsigned u; } v; v.f = f;
    return (ushort)((v.u + 0x7FFFu + ((v.u >> 16) & 1u)) >> 16);
}
__device__ __forceinline__ bf16x8 ldcvt8(const float* p) {
    float4 a = *(const float4*)p;
    float4 b = *(const float4*)(p + 4);
    bf16x8 r;
    r[0] = (short)f2bf(a.x); r[1] = (short)f2bf(a.y);
    r[2] = (short)f2bf(a.z); r[3] = (short)f2bf(a.w);
    r[4] = (short)f2bf(b.x); r[5] = (short)f2bf(b.y);
    r[6] = (short)f2bf(b.z); r[7] = (short)f2bf(b.w);
    return r;
}

// ---------------------------------------------------------------------------
// kE2 (256 blocks x 256 thr): E[mat][b][n] = exp(-(S[b,:] . W[n,0:K]))
// with S computed IN-BLOCK: S[b][n'] = sigmoid(table_row[b] . kn[n']) via
// MFMA into XOR-swizzled bf16 LDS (16x redundant across nt — trivial).
// Step 2: full K=512 contraction, 4 waves = k-quarters, LDS-combined + exp.
// ---------------------------------------------------------------------------
__global__ void __launch_bounds__(256) kE2(const int* __restrict__ sid,
                                           const int* __restrict__ eid,
                                           const float* __restrict__ stu_t,
                                           const float* __restrict__ exer_t,
                                           const float* __restrict__ kn_t,
                                           const float* __restrict__ W1,
                                           const float* __restrict__ W2,
                                           float* __restrict__ E) {
    __shared__ ushort S_lds[32 * 512];      // 32 KB, row=b (1024B), XOR-swizzled
    __shared__ float red[4 * 32 * 33];      // 16.9 KB
    __shared__ int ids[32];
    const int bid = blockIdx.x, t = threadIdx.x;
    const int l = t & 63, w = t >> 6;
    const int mat = bid >> 7, bt = (bid >> 4) & 7, nt = bid & 15;
    const int b0 = bt * 32, n0 = nt * 32;
    if (t < 32) ids[t] = (mat ? eid : sid)[b0 + t];
    __syncthreads();

    // ---- step 1: S-tile (32 b x 512 n), wave w covers n in [128w, 128w+128)
    {
        const float* tab = mat ? exer_t : stu_t;
        const float* ar = tab + (size_t)ids[l & 31] * D_ + (l >> 5) * 8;
        const bf16x8 a0 = ldcvt8(ar),      a1 = ldcvt8(ar + 16),
                     a2 = ldcvt8(ar + 32), a3 = ldcvt8(ar + 48);
#pragma unroll
        for (int tt = 0; tt < 4; tt++) {
            const int ncol = w * 128 + tt * 32 + (l & 31);
            const float* br = kn_t + (size_t)ncol * D_ + (l >> 5) * 8;
            f32x16 acc = ZERO16;
            acc = __builtin_amdgcn_mfma_f32_32x32x16_bf16(a0, ldcvt8(br),      acc, 0, 0, 0);
            acc = __builtin_amdgcn_mfma_f32_32x32x16_bf16(a1, ldcvt8(br + 16), acc, 0, 0, 0);
            acc = __builtin_amdgcn_mfma_f32_32x32x16_bf16(a2, ldcvt8(br + 32), acc, 0, 0, 0);
            acc = __builtin_amdgcn_mfma_f32_32x32x16_bf16(a3, ldcvt8(br + 48), acc, 0, 0, 0);
#pragma unroll
            for (int r = 0; r < 16; r++) {
                const int row = (r & 3) + 8 * (r >> 2) + 4 * (l >> 5);   // b-row
                const int byte = row * 1024 + ((ncol * 2) ^ ((row & 7) << 4));
                *(ushort*)((char*)S_lds + byte) = f2bf(fsig(acc[r]));
            }
        }
    }
    __syncthreads();

    // ---- step 2: E-tile 32b x 32n, k = 512 (wave w = k-quarter)
    {
        const int row = l & 31;                 // A-row (b)
        const int swz = (row & 7) << 4;
        const int kbase = w * 128 + (l >> 5) * 8;
        const float* wr = (mat ? W2 : W1) + (size_t)(n0 + (l & 31)) * KD_ + kbase;
        f32x16 acc = ZERO16;
#pragma unroll
        for (int kk = 0; kk < 8; kk++) {
            const int kel = kbase + kk * 16;
            bf16x8 a = *(const bf16x8*)((const char*)S_lds + row * 1024 + ((kel * 2) ^ swz));
            bf16x8 b = ldcvt8(wr + kk * 16);
            acc = __builtin_amdgcn_mfma_f32_32x32x16_bf16(a, b, acc, 0, 0, 0);
        }
#pragma unroll
        for (int r = 0; r < 16; r++) {
            const int rowc = (r & 3) + 8 * (r >> 2) + 4 * (l >> 5);
            red[w * 1056 + rowc * 33 + (l & 31)] = acc[r];
        }
    }
    __syncthreads();
#pragma unroll
    for (int i = 0; i < 4; i++) {
        const int o = i * 256 + t;
        const int row = (o >> 5) & 31, col = o & 31;
        const float v = red[row * 33 + col] + red[1056 + row * 33 + col]
                      + red[2112 + row * 33 + col] + red[3168 + row * 33 + col];
        E[(size_t)mat * B_ * K_ + (size_t)(b0 + row) * K_ + n0 + col]
            = fexp2(-LOG2E * v);
    }
}

// ---------------------------------------------------------------------------
// kMain (grid (8 kg, 32 bg, 4 ns), 512 thr, LDS 75.3KB -> 2 blocks/CU):
// Phase A: FT[mat][128n][65pad] = exp(-(kn[k].W[n,K:K+D])) computed IN-BLOCK
//          via MFMA (32x redundant, ~1.8us chip-wide) -> padded LDS, writes
//          conflict-free (bank = (n+k)%32).
// Phase B: lane owns k=kg*64+l; wave w owns n in [16w,16w+16); 8 b per block.
//          All operands from LDS (f: 2-way free; e/w3: uniform broadcast).
// Phase C: LDS transpose-reduce (stride-9 rows, conflict-free) -> pPart.
// NO atomics, NO fences, NO FT/S global tensors.
// ---------------------------------------------------------------------------
__global__ void __launch_bounds__(512) kMain(const float* __restrict__ kn_t,
                                             const float* __restrict__ W1,
                                             const float* __restrict__ W2,
                                             const float* __restrict__ Ebase,
                                             const float* __restrict__ W3,
                                             float* __restrict__ pPart) {
    __shared__ float lds[18816];   // FT: [2][128][65] @0 (16640) | es: [2][128][8] @16640 | w3 @18688
    const int t = threadIdx.x, l = t & 63, w = t >> 6;
    const int kg = blockIdx.x, bg = blockIdx.y, ns = blockIdx.z;
    const int b0 = bg * 8;

    // ---- phase A: FT slice (2 mat x 128 n x 64 k); wave w -> tiles 2w, 2w+1
    {
        const int tid0 = w * 2;
        const int mat = tid0 >> 3, kt = (tid0 >> 2) & 1;
        const int krow = kg * 64 + kt * 32 + (l & 31);
        const float* ar = kn_t + (size_t)krow * D_ + (l >> 5) * 8;
        const bf16x8 a0 = ldcvt8(ar),      a1 = ldcvt8(ar + 16),
                     a2 = ldcvt8(ar + 32), a3 = ldcvt8(ar + 48);
        const float* Wm = mat ? W2 : W1;
#pragma unroll
        for (int c = 0; c < 2; c++) {
            const int nt = (tid0 + c) & 3;
            const int nrow = ns * 128 + nt * 32 + (l & 31);
            const float* br = Wm + (size_t)nrow * KD_ + K_ + (l >> 5) * 8;
            f32x16 acc = ZERO16;
            acc = __builtin_amdgcn_mfma_f32_32x32x16_bf16(a0, ldcvt8(br),      acc, 0, 0, 0);
            acc = __builtin_amdgcn_mfma_f32_32x32x16_bf16(a1, ldcvt8(br + 16), acc, 0, 0, 0);
            acc = __builtin_amdgcn_mfma_f32_32x32x16_bf16(a2, ldcvt8(br + 32), acc, 0, 0, 0);
            acc = __builtin_amdgcn_mfma_f32_32x32x16_bf16(a3, ldcvt8(br + 48), acc, 0, 0, 0);
            const int nl = nt * 32 + (l & 31);
#pragma unroll
            for (int r = 0; r < 16; r++) {
                const int kl = kt * 32 + (r & 3) + 8 * (r >> 2) + 4 * (l >> 5);
                lds[mat * 8320 + nl * 65 + kl] = fexp2(-LOG2E * acc[r]);
            }
        }
    }
    // ---- es fill: lds[16640 + mat*1024 + nl*8 + b] = E[mat][b0+b][ns*128+nl]
    {
        const int i = t * 4;
        const int mat = i >> 10, r2 = i & 1023, nl = r2 >> 3, bq = r2 & 7;  // bq in {0,4}
        const float* Em = Ebase + (size_t)mat * B_ * K_ + (size_t)(b0 + bq) * K_
                        + ns * 128 + nl;
        v4f ev; ev.x = Em[0]; ev.y = Em[K_]; ev.z = Em[2 * K_]; ev.w = Em[3 * K_];
        *(v4f*)&lds[16640 + i] = ev;
    }
    if (t < 128) lds[18688 + t] = W3[ns * 128 + t];
    __syncthreads();

    // ---- phase B: 16 n per wave; 8 b per lane; k = l
    v2f acc0 = {0.f, 0.f}, acc1 = {0.f, 0.f}, acc2 = {0.f, 0.f}, acc3 = {0.f, 0.f};
    const int nbase = w * 16;
#pragma unroll 4
    for (int nl = 0; nl < 16; nl++) {
        const int n = nbase + nl;
        const float f1 = lds[n * 65 + l];
        const float f2 = lds[8320 + n * 65 + l];
        const float w3n = lds[18688 + n];
        const v4f e1a = *(const v4f*)&lds[16640 + n * 8];
        const v4f e1b = *(const v4f*)&lds[16640 + n * 8 + 4];
        const v4f e2a = *(const v4f*)&lds[17664 + n * 8];
        const v4f e2b = *(const v4f*)&lds[17664 + n * 8 + 4];
        {
            const v2f e1 = {e1a.x, e1a.y}, e2 = {e2a.x, e2a.y};
            const v2f pd = e1 * f1 + 1.0f, qd = e2 * f2 + 1.0f;
            const v2f den = pd * qd;
            v2f rc; rc.x = frcp(den.x); rc.y = frcp(den.y);
            acc0 += ((qd - pd) * w3n) * rc;
        }
        {
            const v2f e1 = {e1a.z, e1a.w}, e2 = {e2a.z, e2a.w};
            const v2f pd = e1 * f1 + 1.0f, qd = e2 * f2 + 1.0f;
            const v2f den = pd * qd;
            v2f rc; rc.x = frcp(den.x); rc.y = frcp(den.y);
            acc1 += ((qd - pd) * w3n) * rc;
        }
        {
            const v2f e1 = {e1b.x, e1b.y}, e2 = {e2b.x, e2b.y};
            const v2f pd = e1 * f1 + 1.0f, qd = e2 * f2 + 1.0f;
            const v2f den = pd * qd;
            v2f rc; rc.x = frcp(den.x); rc.y = frcp(den.y);
            acc2 += ((qd - pd) * w3n) * rc;
        }
        {
            const v2f e1 = {e1b.z, e1b.w}, e2 = {e2b.z, e2b.w};
            const v2f pd = e1 * f1 + 1.0f, qd = e2 * f2 + 1.0f;
            const v2f den = pd * qd;
            v2f rc; rc.x = frcp(den.x); rc.y = frcp(den.y);
            acc3 += ((qd - pd) * w3n) * rc;
        }
    }

    // ---- phase C: transpose-reduce via LDS (overlay FT region, stride 9)
    __syncthreads();
    {
        const int base = w * 576 + l * 9;
        lds[base + 0] = acc0.x; lds[base + 1] = acc0.y;
        lds[base + 2] = acc1.x; lds[base + 3] = acc1.y;
        lds[base + 4] = acc2.x; lds[base + 5] = acc2.y;
        lds[base + 6] = acc3.x; lds[base + 7] = acc3.y;
    }
    __syncthreads();
    float s = 0.f;
#pragma unroll
    for (int ww = 0; ww < 8; ww++) s += lds[ww * 576 + l * 9 + w];
    pPart[(((size_t)ns * 32 + bg) * 8 + w) * K_ + kg * 64 + l] = s;
}

// ---------------------------------------------------------------------------
// kFin (64 blocks x 256): wave w -> b = bid*4 + w.
// out[b] = sum_k sigmoid(sum_ns part + b3) * kn_emb[b,k] / sum_n kn_emb[b,n]
// ---------------------------------------------------------------------------
__global__ void __launch_bounds__(256) kFin(const float* __restrict__ pPart,
                                            const float* __restrict__ kn_emb,
                                            const float* __restrict__ b3,
                                            float* __restrict__ out) {
    const int t = threadIdx.x, l = t & 63, w = t >> 6;
    const int b = blockIdx.x * 4 + w;
    const int bg = b >> 3, bi = b & 7;
    const float b3v = b3[0];
    const float* p0 = pPart + (((size_t)0 * 32 + bg) * 8 + bi) * K_;
    const float* p1 = pPart + (((size_t)1 * 32 + bg) * 8 + bi) * K_;
    const float* p2 = pPart + (((size_t)2 * 32 + bg) * 8 + bi) * K_;
    const float* p3 = pPart + (((size_t)3 * 32 + bg) * 8 + bi) * K_;
    const float* ke = kn_emb + (size_t)b * K_;
    float num = 0.f, den = 0.f;
#pragma unroll
    for (int c = 0; c < 8; c++) {
        const int kk = c * 64 + l;
        const float sv = p0[kk] + p1[kk] + p2[kk] + p3[kk];
        const float kv = ke[kk];
        num = fmaf(fsig(sv + b3v), kv, num);
        den += kv;
    }
#pragma unroll
    for (int off = 32; off; off >>= 1) {
        num += __shfl_xor(num, off, 64);
        den += __shfl_xor(den, off, 64);
    }
    if (l == 0) out[b] = num / den;
}

extern "C" void kernel_launch(void* const* d_in, const int* in_sizes, int n_in,
                              void* d_out, int out_size, void* d_ws, size_t ws_size,
                              hipStream_t stream) {
    const int*   stu_id     = (const int*)d_in[0];
    const int*   exer_id    = (const int*)d_in[1];
    const float* kn_emb     = (const float*)d_in[2];
    const float* stu_table  = (const float*)d_in[3];
    const float* exer_table = (const float*)d_in[4];
    const float* kn_table   = (const float*)d_in[5];
    const float* W1         = (const float*)d_in[6];
    const float* W2         = (const float*)d_in[7];
    const float* W3         = (const float*)d_in[8];
    const float* b3         = (const float*)d_in[9];
    float* out = (float*)d_out;

    float* ws = (float*)d_ws;
    float* E     = ws;                                 // 2*B*K f
    float* pPart = E + 2 * (size_t)B_ * K_;            // 4*32*8*512 f = 2MB

    kE2<<<256, 256, 0, stream>>>(stu_id, exer_id, stu_table, exer_table,
                                 kn_table, W1, W2, E);
    kMain<<<dim3(8, 32, 4), 512, 0, stream>>>(kn_table, W1, W2, E, W3, pPart);
    kFin<<<64, 256, 0, stream>>>(pPart, kn_emb, b3, out);
}

// Round 9
// 38.297 us; speedup vs baseline: 1.2057x; 1.2057x over previous
//
#include <hip/hip_runtime.h>

#define B_ 256
#define K_ 512
#define D_ 64
#define KD_ 576
#define LOG2E 1.44269504088896340736f

typedef float v2f __attribute__((ext_vector_type(2)));
typedef float v4f __attribute__((ext_vector_type(4)));
typedef short bf16x8 __attribute__((ext_vector_type(8)));
typedef float f32x16 __attribute__((ext_vector_type(16)));

#define ZERO16 {0.f,0.f,0.f,0.f,0.f,0.f,0.f,0.f,0.f,0.f,0.f,0.f,0.f,0.f,0.f,0.f}

__device__ __forceinline__ float fexp2(float x) {
#if __has_builtin(__builtin_amdgcn_exp2f)
    return __builtin_amdgcn_exp2f(x);
#else
    float r; asm("v_exp_f32 %0, %1" : "=v"(r) : "v"(x)); return r;
#endif
}
__device__ __forceinline__ float frcp(float x) {
#if __has_builtin(__builtin_amdgcn_rcpf)
    return __builtin_amdgcn_rcpf(x);
#else
    float r; asm("v_rcp_f32 %0, %1" : "=v"(r) : "v"(x)); return r;
#endif
}
__device__ __forceinline__ float fsig(float x) {
    return frcp(1.0f + fexp2(-LOG2E * x));
}
__device__ __forceinline__ ushort f2bf(float f) {
    union { float f; unsigned u; } v; v.f = f;
    return (ushort)((v.u + 0x7FFFu + ((v.u >> 16) & 1u)) >> 16);
}
__device__ __forceinline__ bf16x8 ldcvt8(const float* p) {
    float4 a = *(const float4*)p;
    float4 b = *(const float4*)(p + 4);
    bf16x8 r;
    r[0] = (short)f2bf(a.x); r[1] = (short)f2bf(a.y);
    r[2] = (short)f2bf(a.z); r[3] = (short)f2bf(a.w);
    r[4] = (short)f2bf(b.x); r[5] = (short)f2bf(b.y);
    r[6] = (short)f2bf(b.z); r[7] = (short)f2bf(b.w);
    return r;
}

// ---------------------------------------------------------------------------
// kPrep2 (384 blocks x 256 thr):
//  [0,256):   E[mat][b][n] = exp(-(S[b,:] . W[n,0:K])) with S computed
//             IN-BLOCK (MFMA -> XOR-swizzled bf16 LDS, 16x redundant, tiny),
//             then full-K contraction (4 waves = k-quarters, LDS-combined).
//  [256,384): FT[mat][n][k] = exp(-(kn[k] . W[n,K:K+D])) transposed via LDS.
//  E-part and FT-part are independent -> run concurrently across CUs.
// ---------------------------------------------------------------------------
__global__ void __launch_bounds__(256) kPrep2(const int* __restrict__ sid,
                                              const int* __restrict__ eid,
                                              const float* __restrict__ stu_t,
                                              const float* __restrict__ exer_t,
                                              const float* __restrict__ kn_t,
                                              const float* __restrict__ W1,
                                              const float* __restrict__ W2,
                                              float* __restrict__ E,
                                              float* __restrict__ FT1,
                                              float* __restrict__ FT2) {
    __shared__ ushort S_lds[32 * 512];      // 32 KB (E-part) / reused by FT-part
    __shared__ float red[4 * 32 * 33];      // 16.9 KB
    __shared__ int ids[32];
    const int bid = blockIdx.x, t = threadIdx.x;
    const int l = t & 63, w = t >> 6;
    if (bid < 256) {
        const int mat = bid >> 7, bt = (bid >> 4) & 7, nt = bid & 15;
        const int b0 = bt * 32, n0 = nt * 32;
        if (t < 32) ids[t] = (mat ? eid : sid)[b0 + t];
        __syncthreads();
        // ---- step 1: S-tile (32 b x 512 n), wave w -> n in [128w, 128w+128)
        {
            const float* tab = mat ? exer_t : stu_t;
            const float* ar = tab + (size_t)ids[l & 31] * D_ + (l >> 5) * 8;
            const bf16x8 a0 = ldcvt8(ar),      a1 = ldcvt8(ar + 16),
                         a2 = ldcvt8(ar + 32), a3 = ldcvt8(ar + 48);
#pragma unroll
            for (int tt = 0; tt < 4; tt++) {
                const int ncol = w * 128 + tt * 32 + (l & 31);
                const float* br = kn_t + (size_t)ncol * D_ + (l >> 5) * 8;
                f32x16 acc = ZERO16;
                acc = __builtin_amdgcn_mfma_f32_32x32x16_bf16(a0, ldcvt8(br),      acc, 0, 0, 0);
                acc = __builtin_amdgcn_mfma_f32_32x32x16_bf16(a1, ldcvt8(br + 16), acc, 0, 0, 0);
                acc = __builtin_amdgcn_mfma_f32_32x32x16_bf16(a2, ldcvt8(br + 32), acc, 0, 0, 0);
                acc = __builtin_amdgcn_mfma_f32_32x32x16_bf16(a3, ldcvt8(br + 48), acc, 0, 0, 0);
#pragma unroll
                for (int r = 0; r < 16; r++) {
                    const int row = (r & 3) + 8 * (r >> 2) + 4 * (l >> 5);   // b-row
                    const int byte = row * 1024 + ((ncol * 2) ^ ((row & 7) << 4));
                    *(ushort*)((char*)S_lds + byte) = f2bf(fsig(acc[r]));
                }
            }
        }
        __syncthreads();
        // ---- step 2: E-tile 32b x 32n, k = 512 (wave w = k-quarter)
        {
            const int row = l & 31;
            const int swz = (row & 7) << 4;
            const int kbase = w * 128 + (l >> 5) * 8;
            const float* wr = (mat ? W2 : W1) + (size_t)(n0 + (l & 31)) * KD_ + kbase;
            f32x16 acc = ZERO16;
#pragma unroll
            for (int kk = 0; kk < 8; kk++) {
                const int kel = kbase + kk * 16;
                bf16x8 a = *(const bf16x8*)((const char*)S_lds + row * 1024 + ((kel * 2) ^ swz));
                bf16x8 b = ldcvt8(wr + kk * 16);
                acc = __builtin_amdgcn_mfma_f32_32x32x16_bf16(a, b, acc, 0, 0, 0);
            }
#pragma unroll
            for (int r = 0; r < 16; r++) {
                const int rowc = (r & 3) + 8 * (r >> 2) + 4 * (l >> 5);
                red[w * 1056 + rowc * 33 + (l & 31)] = acc[r];
            }
        }
        __syncthreads();
#pragma unroll
        for (int i = 0; i < 4; i++) {
            const int o = i * 256 + t;
            const int row = (o >> 5) & 31, col = o & 31;
            const float v = red[row * 33 + col] + red[1056 + row * 33 + col]
                          + red[2112 + row * 33 + col] + red[3168 + row * 33 + col];
            E[(size_t)mat * B_ * K_ + (size_t)(b0 + row) * K_ + n0 + col]
                = fexp2(-LOG2E * v);
        }
    } else {
        // ---- FT-part (R7 kEF F-segment): transpose via LDS
        float* shm = (float*)S_lds;   // 64*65 floats = 16640 B
        const int fid = bid - 256;
        const int mat = fid >> 6, kt = (fid >> 3) & 7, nt = fid & 7;
        const int k0 = kt * 64, n0 = nt * 64;
        const int krow = k0 + (w & 1) * 32 + (l & 31);
        const int ncol = n0 + (w >> 1) * 32 + (l & 31);
        const int dk = (l >> 5) * 8;
        const float* Wm = mat ? W2 : W1;
        const float* ar = kn_t + (size_t)krow * D_;
        const float* br = Wm + (size_t)ncol * KD_ + K_;
        f32x16 acc = ZERO16;
#pragma unroll
        for (int kk = 0; kk < 4; kk++) {
            bf16x8 a = ldcvt8(ar + kk * 16 + dk);
            bf16x8 b = ldcvt8(br + kk * 16 + dk);
            acc = __builtin_amdgcn_mfma_f32_32x32x16_bf16(a, b, acc, 0, 0, 0);
        }
        const int nl_ = (w >> 1) * 32 + (l & 31);
#pragma unroll
        for (int r = 0; r < 16; r++) {
            const int row = (r & 3) + 8 * (r >> 2) + 4 * (l >> 5);
            shm[nl_ * 65 + (w & 1) * 32 + row] = fexp2(-LOG2E * acc[r]);
        }
        __syncthreads();
        float* Fo = mat ? FT2 : FT1;
#pragma unroll
        for (int i = 0; i < 16; i++) {
            const int q = i * 256 + t;
            const int r_ = q >> 6, c_ = q & 63;
            Fo[(size_t)(n0 + r_) * K_ + k0 + c_] = shm[r_ * 65 + c_];
        }
    }
}

// ---------------------------------------------------------------------------
// kMain: grid (8 kg, 32 bg, 4 ns) = 1024 blocks (4/CU, 32 waves/CU), 512 thr.
// Lane owns k = kg*64+l; wave w handles n-slice [ns*128+16w, +16); 8 b/block.
// e-values: wave-uniform LDS broadcast; FT loads coalesced 256B/wave from L2.
// In-block n-slice sum via LDS stride-9 transpose; f32 partials out. NO atomics.
// ---------------------------------------------------------------------------
__global__ void __launch_bounds__(512) kMain(const float* __restrict__ FT1,
                                             const float* __restrict__ FT2,
                                             const float* __restrict__ Ebase,
                                             const float* __restrict__ W3,
                                             float* __restrict__ pPart) {
    __shared__ float lds[4608];   // es [2][128][8] @0 (2048) | w3 @2048 (128) | phase-C overlay
    const int t = threadIdx.x;
    const int l = t & 63, w = t >> 6;
    const int kg = blockIdx.x, bg = blockIdx.y, ns = blockIdx.z;
    const int b0 = bg * 8;
    const int k = kg * 64 + l;

    // es fill: lds[mat*1024 + nl*8 + b] = E[mat][b0+b][ns*128+nl]  (coalesced)
#pragma unroll
    for (int c = 0; c < 2; c++) {
        const int combo = w * 2 + c;
        const int mat = combo >> 3, b = combo & 7;
        const float* src = Ebase + (size_t)mat * B_ * K_ + (size_t)(b0 + b) * K_
                         + ns * 128;
#pragma unroll
        for (int j = 0; j < 2; j++) {
            const int nl = j * 64 + l;
            lds[mat * 1024 + nl * 8 + b] = src[nl];
        }
    }
    if (t < 128) lds[2048 + t] = W3[ns * 128 + t];
    __syncthreads();

    const int nbase = w * 16;
    const float* f1p = FT1 + (size_t)(ns * 128 + nbase) * K_ + k;
    const float* f2p = FT2 + (size_t)(ns * 128 + nbase) * K_ + k;

    v2f acc0 = {0.f, 0.f}, acc1 = {0.f, 0.f}, acc2 = {0.f, 0.f}, acc3 = {0.f, 0.f};

#pragma unroll 4
    for (int nl = 0; nl < 16; nl++) {
        const float f1 = f1p[(size_t)nl * K_];
        const float f2 = f2p[(size_t)nl * K_];
        const int n = nbase + nl;
        const float w3n = lds[2048 + n];
        const v4f e1a = *(const v4f*)&lds[n * 8];
        const v4f e1b = *(const v4f*)&lds[n * 8 + 4];
        const v4f e2a = *(const v4f*)&lds[1024 + n * 8];
        const v4f e2b = *(const v4f*)&lds[1024 + n * 8 + 4];
        {
            const v2f e1 = {e1a.x, e1a.y}, e2 = {e2a.x, e2a.y};
            const v2f pd = e1 * f1 + 1.0f, qd = e2 * f2 + 1.0f;
            const v2f den = pd * qd;
            v2f rc; rc.x = frcp(den.x); rc.y = frcp(den.y);
            acc0 += ((qd - pd) * w3n) * rc;
        }
        {
            const v2f e1 = {e1a.z, e1a.w}, e2 = {e2a.z, e2a.w};
            const v2f pd = e1 * f1 + 1.0f, qd = e2 * f2 + 1.0f;
            const v2f den = pd * qd;
            v2f rc; rc.x = frcp(den.x); rc.y = frcp(den.y);
            acc1 += ((qd - pd) * w3n) * rc;
        }
        {
            const v2f e1 = {e1b.x, e1b.y}, e2 = {e2b.x, e2b.y};
            const v2f pd = e1 * f1 + 1.0f, qd = e2 * f2 + 1.0f;
            const v2f den = pd * qd;
            v2f rc; rc.x = frcp(den.x); rc.y = frcp(den.y);
            acc2 += ((qd - pd) * w3n) * rc;
        }
        {
            const v2f e1 = {e1b.z, e1b.w}, e2 = {e2b.z, e2b.w};
            const v2f pd = e1 * f1 + 1.0f, qd = e2 * f2 + 1.0f;
            const v2f den = pd * qd;
            v2f rc; rc.x = frcp(den.x); rc.y = frcp(den.y);
            acc3 += ((qd - pd) * w3n) * rc;
        }
    }

    __syncthreads();   // es reads done -> safe to overwrite
    {
        float* sa = lds + w * 576 + l * 9;   // sacc[w][k_l][b], stride 9 (conflict-lite)
        *(v2f*)(sa + 0) = acc0;
        *(v2f*)(sa + 2) = acc1;
        *(v2f*)(sa + 4) = acc2;
        *(v2f*)(sa + 6) = acc3;
    }
    __syncthreads();
    // thread (w,l): b = w, k_l = l; sum the 8 wave n-slices
    float s = 0.f;
#pragma unroll
    for (int ww = 0; ww < 8; ww++) s += lds[ww * 576 + l * 9 + w];
    pPart[(((size_t)ns * 32 + bg) * 8 + w) * K_ + kg * 64 + l] = s;
}

// ---------------------------------------------------------------------------
// kFin (64 blocks x 256): wave w -> b = bid*4 + w.
// out[b] = sum_k sigmoid(sum_ns part + b3) * kn_emb[b,k] / sum_n kn_emb[b,n]
// ---------------------------------------------------------------------------
__global__ void __launch_bounds__(256) kFin(const float* __restrict__ pPart,
                                            const float* __restrict__ kn_emb,
                                            const float* __restrict__ b3,
                                            float* __restrict__ out) {
    const int t = threadIdx.x, l = t & 63, w = t >> 6;
    const int b = blockIdx.x * 4 + w;
    const int bg = b >> 3, bi = b & 7;
    const float b3v = b3[0];
    const float* p0 = pPart + (((size_t)0 * 32 + bg) * 8 + bi) * K_;
    const float* p1 = pPart + (((size_t)1 * 32 + bg) * 8 + bi) * K_;
    const float* p2 = pPart + (((size_t)2 * 32 + bg) * 8 + bi) * K_;
    const float* p3 = pPart + (((size_t)3 * 32 + bg) * 8 + bi) * K_;
    const float* ke = kn_emb + (size_t)b * K_;
    float num = 0.f, den = 0.f;
#pragma unroll
    for (int c = 0; c < 8; c++) {
        const int kk = c * 64 + l;
        const float sv = (p0[kk] + p1[kk]) + (p2[kk] + p3[kk]);
        const float kv = ke[kk];
        num = fmaf(fsig(sv + b3v), kv, num);
        den += kv;
    }
#pragma unroll
    for (int off = 32; off; off >>= 1) {
        num += __shfl_xor(num, off, 64);
        den += __shfl_xor(den, off, 64);
    }
    if (l == 0) out[b] = num / den;
}

extern "C" void kernel_launch(void* const* d_in, const int* in_sizes, int n_in,
                              void* d_out, int out_size, void* d_ws, size_t ws_size,
                              hipStream_t stream) {
    const int*   stu_id     = (const int*)d_in[0];
    const int*   exer_id    = (const int*)d_in[1];
    const float* kn_emb     = (const float*)d_in[2];
    const float* stu_table  = (const float*)d_in[3];
    const float* exer_table = (const float*)d_in[4];
    const float* kn_table   = (const float*)d_in[5];
    const float* W1         = (const float*)d_in[6];
    const float* W2         = (const float*)d_in[7];
    const float* W3         = (const float*)d_in[8];
    const float* b3         = (const float*)d_in[9];
    float* out = (float*)d_out;

    float* ws = (float*)d_ws;
    float* FT1   = ws;                                 // K*K f
    float* FT2   = FT1 + (size_t)K_ * K_;              // K*K f
    float* E     = FT2 + (size_t)K_ * K_;              // 2*B*K f
    float* pPart = E + 2 * (size_t)B_ * K_;            // 4*32*8*512 f = 2MB

    kPrep2<<<384, 256, 0, stream>>>(stu_id, exer_id, stu_table, exer_table,
                                    kn_table, W1, W2, E, FT1, FT2);
    kMain<<<dim3(8, 32, 4), 512, 0, stream>>>(FT1, FT2, E, W3, pPart);
    kFin<<<64, 256, 0, stream>>>(pPart, kn_emb, b3, out);
}

// Round 10
// 38.157 us; speedup vs baseline: 1.2102x; 1.0037x over previous
//
#include <hip/hip_runtime.h>

#define B_ 256
#define K_ 512
#define D_ 64
#define KD_ 576
#define LOG2E 1.44269504088896340736f

typedef float v2f __attribute__((ext_vector_type(2)));
typedef float v4f __attribute__((ext_vector_type(4)));
typedef short bf16x8 __attribute__((ext_vector_type(8)));
typedef float f32x16 __attribute__((ext_vector_type(16)));

#define ZERO16 {0.f,0.f,0.f,0.f,0.f,0.f,0.f,0.f,0.f,0.f,0.f,0.f,0.f,0.f,0.f,0.f}

__device__ __forceinline__ float fexp2(float x) {
#if __has_builtin(__builtin_amdgcn_exp2f)
    return __builtin_amdgcn_exp2f(x);
#else
    float r; asm("v_exp_f32 %0, %1" : "=v"(r) : "v"(x)); return r;
#endif
}
__device__ __forceinline__ float frcp(float x) {
#if __has_builtin(__builtin_amdgcn_rcpf)
    return __builtin_amdgcn_rcpf(x);
#else
    float r; asm("v_rcp_f32 %0, %1" : "=v"(r) : "v"(x)); return r;
#endif
}
__device__ __forceinline__ float fsig(float x) {
    return frcp(1.0f + fexp2(-LOG2E * x));
}
__device__ __forceinline__ ushort f2bf(float f) {
    union { float f; unsigned u; } v; v.f = f;
    return (ushort)((v.u + 0x7FFFu + ((v.u >> 16) & 1u)) >> 16);
}
__device__ __forceinline__ bf16x8 ldcvt8(const float* p) {
    float4 a = *(const float4*)p;
    float4 b = *(const float4*)(p + 4);
    bf16x8 r;
    r[0] = (short)f2bf(a.x); r[1] = (short)f2bf(a.y);
    r[2] = (short)f2bf(a.z); r[3] = (short)f2bf(a.w);
    r[4] = (short)f2bf(b.x); r[5] = (short)f2bf(b.y);
    r[6] = (short)f2bf(b.z); r[7] = (short)f2bf(b.w);
    return r;
}

// ---------------------------------------------------------------------------
// kSF (192 blocks x 256 thr) — two INDEPENDENT segments, co-scheduled:
//  [0,64):   Sb[tab][b][n] = bf16(sigmoid(table_row[b] . kn[n]))      MFMA
//  [64,192): FT[mat][n][k] = exp(-(kn[k] . W[n,K:K+D])) fp32, LDS-transposed
// ---------------------------------------------------------------------------
__global__ void __launch_bounds__(256) kSF(const int* __restrict__ sid,
                                           const int* __restrict__ eid,
                                           const float* __restrict__ stu_t,
                                           const float* __restrict__ exer_t,
                                           const float* __restrict__ kn_t,
                                           const float* __restrict__ W1,
                                           const float* __restrict__ W2,
                                           ushort* __restrict__ Sbu,
                                           float* __restrict__ FT1,
                                           float* __restrict__ FT2) {
    __shared__ float shm[64 * 65];
    const int bid = blockIdx.x, t = threadIdx.x;
    const int l = t & 63, w = t >> 6;
    const int dk = (l >> 5) * 8;
    if (bid < 64) {
        const int tab = bid >> 5, bt = (bid >> 3) & 3, nt = bid & 7;
        const int b0 = bt * 64, n0 = nt * 64;
        const int brow = b0 + (w & 1) * 32 + (l & 31);
        const int ncol = n0 + (w >> 1) * 32 + (l & 31);
        const int id = (tab ? eid : sid)[brow];
        const float* ar = (tab ? exer_t : stu_t) + (size_t)id * D_;
        const float* br = kn_t + (size_t)ncol * D_;
        f32x16 acc = ZERO16;
#pragma unroll
        for (int kk = 0; kk < 4; kk++) {
            bf16x8 a = ldcvt8(ar + kk * 16 + dk);
            bf16x8 b = ldcvt8(br + kk * 16 + dk);
            acc = __builtin_amdgcn_mfma_f32_32x32x16_bf16(a, b, acc, 0, 0, 0);
        }
        ushort* So = Sbu + (size_t)tab * B_ * K_;
#pragma unroll
        for (int r = 0; r < 16; r++) {
            const int row = (r & 3) + 8 * (r >> 2) + 4 * (l >> 5);
            So[(size_t)(b0 + (w & 1) * 32 + row) * K_ + ncol] = f2bf(fsig(acc[r]));
        }
    } else {
        const int fid = bid - 64;
        const int mat = fid >> 6, kt = (fid >> 3) & 7, nt = fid & 7;
        const int k0 = kt * 64, n0 = nt * 64;
        const int krow = k0 + (w & 1) * 32 + (l & 31);
        const int ncol = n0 + (w >> 1) * 32 + (l & 31);
        const float* Wm = mat ? W2 : W1;
        const float* ar = kn_t + (size_t)krow * D_;
        const float* br = Wm + (size_t)ncol * KD_ + K_;
        f32x16 acc = ZERO16;
#pragma unroll
        for (int kk = 0; kk < 4; kk++) {
            bf16x8 a = ldcvt8(ar + kk * 16 + dk);
            bf16x8 b = ldcvt8(br + kk * 16 + dk);
            acc = __builtin_amdgcn_mfma_f32_32x32x16_bf16(a, b, acc, 0, 0, 0);
        }
        const int nl_ = (w >> 1) * 32 + (l & 31);
#pragma unroll
        for (int r = 0; r < 16; r++) {
            const int row = (r & 3) + 8 * (r >> 2) + 4 * (l >> 5);
            shm[nl_ * 65 + (w & 1) * 32 + row] = fexp2(-LOG2E * acc[r]);
        }
        __syncthreads();
        float* Fo = mat ? FT2 : FT1;
#pragma unroll
        for (int i = 0; i < 16; i++) {
            const int q = i * 256 + t;
            const int r_ = q >> 6, c_ = q & 63;
            Fo[(size_t)(n0 + r_) * K_ + k0 + c_] = shm[r_ * 65 + c_];
        }
    }
}

// ---------------------------------------------------------------------------
// kE (256 blocks x 256 thr): E[mat][b][n] = exp(-(S[b,:] . W[n,0:K]))
// 32b x 32n tile, 4 waves = k-quarters (128 k each), combined in LDS.
// ---------------------------------------------------------------------------
__global__ void __launch_bounds__(256) kE(const ushort* __restrict__ Sbu,
                                          const float* __restrict__ W1,
                                          const float* __restrict__ W2,
                                          float* __restrict__ E) {
    __shared__ float shm[4224];
    const int bid = blockIdx.x, t = threadIdx.x;
    const int l = t & 63, w = t >> 6;
    const int mat = bid >> 7, bt = (bid >> 4) & 7, nt = bid & 15;
    const int b0 = bt * 32, n0 = nt * 32;
    const int arow = b0 + (l & 31);
    const int nrow = n0 + (l & 31);
    const int koff = w * 128 + (l >> 5) * 8;
    const short* Sp = (const short*)Sbu + (size_t)(mat * B_ + arow) * K_ + koff;
    const float* Wp = (mat ? W2 : W1) + (size_t)nrow * KD_ + koff;
    f32x16 acc = ZERO16;
#pragma unroll
    for (int kk = 0; kk < 8; kk++) {
        bf16x8 a = *(const bf16x8*)(Sp + kk * 16);
        bf16x8 b = ldcvt8(Wp + kk * 16);
        acc = __builtin_amdgcn_mfma_f32_32x32x16_bf16(a, b, acc, 0, 0, 0);
    }
#pragma unroll
    for (int r = 0; r < 16; r++) {
        const int row = (r & 3) + 8 * (r >> 2) + 4 * (l >> 5);
        shm[w * 1056 + row * 33 + (l & 31)] = acc[r];
    }
    __syncthreads();
#pragma unroll
    for (int i = 0; i < 4; i++) {
        const int o = i * 256 + t;
        const int row = (o >> 5) & 31, col = o & 31;
        const float v = shm[row * 33 + col] + shm[1056 + row * 33 + col]
                      + shm[2112 + row * 33 + col] + shm[3168 + row * 33 + col];
        E[(size_t)mat * B_ * K_ + (size_t)(b0 + row) * K_ + n0 + col]
            = fexp2(-LOG2E * v);
    }
}

// ---------------------------------------------------------------------------
// kMain v2: grid (2 kg, 16 bG, 16 ns) = 512 blocks, 512 thr (8 waves).
// Lane owns 4 k (float4 FT loads, 1KB/wave coalesced) x 4 b (one b128/mat).
// Wave = (bg = w&3, nh = w>>2); block = 256k x 16b x 32n.
// Per nl: 2 ds_read_b128 + 1 b32 for 16 pairs (4x less LDS-issue than R7).
// 2-way cross-wave n-reduce in LDS; pPart[16 ns][B][K] partials. NO atomics.
// ---------------------------------------------------------------------------
__global__ void __launch_bounds__(512) kMain(const float* __restrict__ FT1,
                                             const float* __restrict__ FT2,
                                             const float* __restrict__ Ebase,
                                             const float* __restrict__ W3,
                                             float* __restrict__ pPart) {
    __shared__ float es[2][32][20];     // padded 20 -> b128-aligned, low conflict
    __shared__ float w3s[32];
    __shared__ float sacc[4][64][20];   // phase-C buffer (separate region)
    const int t = threadIdx.x, l = t & 63, w = t >> 6;
    const int kg = blockIdx.x, bG = blockIdx.y, ns = blockIdx.z;
    const int b0 = bG * 16, n0 = ns * 32;
    const int k = kg * 256 + l * 4;

    // es fill: es[mat][nl][bl] = E[mat][b0+bl][n0+nl]   (coalesced reads)
#pragma unroll
    for (int it = 0; it < 2; it++) {
        const int idx = it * 512 + t;
        const int mat = idx >> 9, r = idx & 511, bl = r >> 5, nl = r & 31;
        es[mat][nl][bl] = Ebase[(size_t)mat * B_ * K_ + (size_t)(b0 + bl) * K_ + n0 + nl];
    }
    if (t < 32) w3s[t] = W3[n0 + t];
    __syncthreads();

    const int bg = w & 3, nh = w >> 2;
    const int wb0 = bg * 4;
    const float* f1p = FT1 + (size_t)(n0 + nh * 16) * K_ + k;
    const float* f2p = FT2 + (size_t)(n0 + nh * 16) * K_ + k;

    v4f acc0 = {0.f,0.f,0.f,0.f}, acc1 = {0.f,0.f,0.f,0.f};
    v4f acc2 = {0.f,0.f,0.f,0.f}, acc3 = {0.f,0.f,0.f,0.f};

#pragma unroll 4
    for (int nl = 0; nl < 16; nl++) {
        const int n = nh * 16 + nl;
        const v4f f1 = *(const v4f*)(f1p + (size_t)nl * K_);
        const v4f f2 = *(const v4f*)(f2p + (size_t)nl * K_);
        const float w3n = w3s[n];
        const v4f e1 = *(const v4f*)&es[0][n][wb0];   // broadcast b128
        const v4f e2 = *(const v4f*)&es[1][n][wb0];
        {
            const v4f pd = e1.x * f1 + 1.0f, qd = e2.x * f2 + 1.0f;
            const v4f den = pd * qd;
            v4f rc; rc.x = frcp(den.x); rc.y = frcp(den.y);
            rc.z = frcp(den.z); rc.w = frcp(den.w);
            acc0 += ((qd - pd) * w3n) * rc;
        }
        {
            const v4f pd = e1.y * f1 + 1.0f, qd = e2.y * f2 + 1.0f;
            const v4f den = pd * qd;
            v4f rc; rc.x = frcp(den.x); rc.y = frcp(den.y);
            rc.z = frcp(den.z); rc.w = frcp(den.w);
            acc1 += ((qd - pd) * w3n) * rc;
        }
        {
            const v4f pd = e1.z * f1 + 1.0f, qd = e2.z * f2 + 1.0f;
            const v4f den = pd * qd;
            v4f rc; rc.x = frcp(den.x); rc.y = frcp(den.y);
            rc.z = frcp(den.z); rc.w = frcp(den.w);
            acc2 += ((qd - pd) * w3n) * rc;
        }
        {
            const v4f pd = e1.w * f1 + 1.0f, qd = e2.w * f2 + 1.0f;
            const v4f den = pd * qd;
            v4f rc; rc.x = frcp(den.x); rc.y = frcp(den.y);
            rc.z = frcp(den.z); rc.w = frcp(den.w);
            acc3 += ((qd - pd) * w3n) * rc;
        }
    }

    // phase C: nh=0 parks in LDS; nh=1 adds and writes pPart (coalesced)
    if (nh == 0) {
        *(v4f*)&sacc[bg][l][0]  = acc0;
        *(v4f*)&sacc[bg][l][4]  = acc1;
        *(v4f*)&sacc[bg][l][8]  = acc2;
        *(v4f*)&sacc[bg][l][12] = acc3;
    }
    __syncthreads();
    if (nh == 1) {
        const v4f o0 = acc0 + *(const v4f*)&sacc[bg][l][0];
        const v4f o1 = acc1 + *(const v4f*)&sacc[bg][l][4];
        const v4f o2 = acc2 + *(const v4f*)&sacc[bg][l][8];
        const v4f o3 = acc3 + *(const v4f*)&sacc[bg][l][12];
        float* po = pPart + ((size_t)ns * B_ + b0 + wb0) * K_ + k;
        *(v4f*)(po)          = o0;
        *(v4f*)(po + K_)     = o1;
        *(v4f*)(po + 2 * K_) = o2;
        *(v4f*)(po + 3 * K_) = o3;
    }
}

// ---------------------------------------------------------------------------
// kFin (64 blocks x 256): wave w -> b = bid*4 + w.
// out[b] = sum_k sigmoid(sum_{ns} pPart + b3) * kn_emb[b,k] / sum_n kn_emb[b,n]
// ---------------------------------------------------------------------------
__global__ void __launch_bounds__(256) kFin(const float* __restrict__ pPart,
                                            const float* __restrict__ kn_emb,
                                            const float* __restrict__ b3,
                                            float* __restrict__ out) {
    const int t = threadIdx.x, l = t & 63, w = t >> 6;
    const int b = blockIdx.x * 4 + w;
    const float b3v = b3[0];
    const float* ke = kn_emb + (size_t)b * K_;
    float num = 0.f, den = 0.f;
#pragma unroll
    for (int c = 0; c < 8; c++) {
        const int kk = c * 64 + l;
        float sv = 0.f;
#pragma unroll
        for (int s = 0; s < 16; s++)
            sv += pPart[((size_t)s * B_ + b) * K_ + kk];
        const float kv = ke[kk];
        num = fmaf(fsig(sv + b3v), kv, num);
        den += kv;
    }
#pragma unroll
    for (int off = 32; off; off >>= 1) {
        num += __shfl_xor(num, off, 64);
        den += __shfl_xor(den, off, 64);
    }
    if (l == 0) out[b] = num / den;
}

extern "C" void kernel_launch(void* const* d_in, const int* in_sizes, int n_in,
                              void* d_out, int out_size, void* d_ws, size_t ws_size,
                              hipStream_t stream) {
    const int*   stu_id     = (const int*)d_in[0];
    const int*   exer_id    = (const int*)d_in[1];
    const float* kn_emb     = (const float*)d_in[2];
    const float* stu_table  = (const float*)d_in[3];
    const float* exer_table = (const float*)d_in[4];
    const float* kn_table   = (const float*)d_in[5];
    const float* W1         = (const float*)d_in[6];
    const float* W2         = (const float*)d_in[7];
    const float* W3         = (const float*)d_in[8];
    const float* b3         = (const float*)d_in[9];
    float* out = (float*)d_out;

    float* ws = (float*)d_ws;
    float* FT1   = ws;                                 // K*K f
    float* FT2   = FT1 + (size_t)K_ * K_;              // K*K f
    float* E     = FT2 + (size_t)K_ * K_;              // 2*B*K f
    ushort* Sbu  = (ushort*)(E + 2 * (size_t)B_ * K_); // 2*B*K ushorts
    float* pPart = (float*)(Sbu + 2 * (size_t)B_ * K_);// 16*B*K f = 8 MB

    kSF<<<192, 256, 0, stream>>>(stu_id, exer_id, stu_table, exer_table,
                                 kn_table, W1, W2, Sbu, FT1, FT2);
    kE<<<256, 256, 0, stream>>>(Sbu, W1, W2, E);
    kMain<<<dim3(2, 16, 16), 512, 0, stream>>>(FT1, FT2, E, W3, pPart);
    kFin<<<64, 256, 0, stream>>>(pPart, kn_emb, b3, out);
}

// Round 11
// 37.194 us; speedup vs baseline: 1.2415x; 1.0259x over previous
//
#include <hip/hip_runtime.h>

#define B_ 256
#define K_ 512
#define D_ 64
#define KD_ 576
#define LOG2E 1.44269504088896340736f

typedef float v4f __attribute__((ext_vector_type(4)));
typedef short bf16x8 __attribute__((ext_vector_type(8)));
typedef float f32x16 __attribute__((ext_vector_type(16)));

#define ZERO16 {0.f,0.f,0.f,0.f,0.f,0.f,0.f,0.f,0.f,0.f,0.f,0.f,0.f,0.f,0.f,0.f}

__device__ __forceinline__ float fexp2(float x) {
#if __has_builtin(__builtin_amdgcn_exp2f)
    return __builtin_amdgcn_exp2f(x);
#else
    float r; asm("v_exp_f32 %0, %1" : "=v"(r) : "v"(x)); return r;
#endif
}
__device__ __forceinline__ float frcp(float x) {
#if __has_builtin(__builtin_amdgcn_rcpf)
    return __builtin_amdgcn_rcpf(x);
#else
    float r; asm("v_rcp_f32 %0, %1" : "=v"(r) : "v"(x)); return r;
#endif
}
__device__ __forceinline__ float fsig(float x) {
    return frcp(1.0f + fexp2(-LOG2E * x));
}
__device__ __forceinline__ ushort f2bf(float f) {
    union { float f; unsigned u; } v; v.f = f;
    return (ushort)((v.u + 0x7FFFu + ((v.u >> 16) & 1u)) >> 16);
}
__device__ __forceinline__ bf16x8 ldcvt8(const float* p) {
    float4 a = *(const float4*)p;
    float4 b = *(const float4*)(p + 4);
    bf16x8 r;
    r[0] = (short)f2bf(a.x); r[1] = (short)f2bf(a.y);
    r[2] = (short)f2bf(a.z); r[3] = (short)f2bf(a.w);
    r[4] = (short)f2bf(b.x); r[5] = (short)f2bf(b.y);
    r[6] = (short)f2bf(b.z); r[7] = (short)f2bf(b.w);
    return r;
}

// ---------------------------------------------------------------------------
// kS (64 blocks x 256): Sb[tab][b][n] = bf16(sigmoid(table_row[b] . kn[n]))
// (R7-verbatim)
// ---------------------------------------------------------------------------
__global__ void __launch_bounds__(256) kS(const int* __restrict__ sid,
                                          const int* __restrict__ eid,
                                          const float* __restrict__ stu_t,
                                          const float* __restrict__ exer_t,
                                          const float* __restrict__ kn_t,
                                          ushort* __restrict__ Sbu) {
    const int bid = blockIdx.x, t = threadIdx.x;
    const int l = t & 63, w = t >> 6;
    const int dk = (l >> 5) * 8;
    const int tab = bid >> 5, bt = (bid >> 3) & 3, nt = bid & 7;
    const int b0 = bt * 64, n0 = nt * 64;
    const int brow = b0 + (w & 1) * 32 + (l & 31);
    const int ncol = n0 + (w >> 1) * 32 + (l & 31);
    const int id = (tab ? eid : sid)[brow];
    const float* ar = (tab ? exer_t : stu_t) + (size_t)id * D_;
    const float* br = kn_t + (size_t)ncol * D_;
    f32x16 acc = ZERO16;
#pragma unroll
    for (int kk = 0; kk < 4; kk++) {
        bf16x8 a = ldcvt8(ar + kk * 16 + dk);
        bf16x8 b = ldcvt8(br + kk * 16 + dk);
        acc = __builtin_amdgcn_mfma_f32_32x32x16_bf16(a, b, acc, 0, 0, 0);
    }
    ushort* So = Sbu + (size_t)tab * B_ * K_;
#pragma unroll
    for (int r = 0; r < 16; r++) {
        const int row = (r & 3) + 8 * (r >> 2) + 4 * (l >> 5);
        So[(size_t)(b0 + (w & 1) * 32 + row) * K_ + ncol] = f2bf(fsig(acc[r]));
    }
}

// ---------------------------------------------------------------------------
// kEF (384 blocks x 256) — R7-verbatim:
//  [0,256):   E[mat][b][n] = exp(-(S[b,:] . W[n,0:K]))   32b x 32n tile
//  [256,384): FT[mat][n][k] = exp(-(kn[k] . W[n,K:K+D])) LDS-transposed
// ---------------------------------------------------------------------------
__global__ void __launch_bounds__(256) kEF(const ushort* __restrict__ Sbu,
                                           const float* __restrict__ W1,
                                           const float* __restrict__ W2,
                                           const float* __restrict__ kn_t,
                                           float* __restrict__ E,
                                           float* __restrict__ FT1,
                                           float* __restrict__ FT2) {
    __shared__ float shm[4224];
    const int bid = blockIdx.x, t = threadIdx.x;
    const int l = t & 63, w = t >> 6;
    if (bid < 256) {
        const int mat = bid >> 7, bt = (bid >> 4) & 7, nt = bid & 15;
        const int b0 = bt * 32, n0 = nt * 32;
        const int arow = b0 + (l & 31);
        const int nrow = n0 + (l & 31);
        const int koff = w * 128 + (l >> 5) * 8;
        const short* Sp = (const short*)Sbu + (size_t)(mat * B_ + arow) * K_ + koff;
        const float* Wp = (mat ? W2 : W1) + (size_t)nrow * KD_ + koff;
        f32x16 acc = ZERO16;
#pragma unroll
        for (int kk = 0; kk < 8; kk++) {
            bf16x8 a = *(const bf16x8*)(Sp + kk * 16);
            bf16x8 b = ldcvt8(Wp + kk * 16);
            acc = __builtin_amdgcn_mfma_f32_32x32x16_bf16(a, b, acc, 0, 0, 0);
        }
#pragma unroll
        for (int r = 0; r < 16; r++) {
            const int row = (r & 3) + 8 * (r >> 2) + 4 * (l >> 5);
            shm[w * 1056 + row * 33 + (l & 31)] = acc[r];
        }
        __syncthreads();
#pragma unroll
        for (int i = 0; i < 4; i++) {
            const int o = i * 256 + t;
            const int row = (o >> 5) & 31, col = o & 31;
            const float v = shm[row * 33 + col] + shm[1056 + row * 33 + col]
                          + shm[2112 + row * 33 + col] + shm[3168 + row * 33 + col];
            E[(size_t)mat * B_ * K_ + (size_t)(b0 + row) * K_ + n0 + col]
                = fexp2(-LOG2E * v);
        }
    } else {
        const int fid = bid - 256;
        const int mat = fid >> 6, kt = (fid >> 3) & 7, nt = fid & 7;
        const int k0 = kt * 64, n0 = nt * 64;
        const int krow = k0 + (w & 1) * 32 + (l & 31);
        const int ncol = n0 + (w >> 1) * 32 + (l & 31);
        const int dk = (l >> 5) * 8;
        const float* Wm = mat ? W2 : W1;
        const float* ar = kn_t + (size_t)krow * D_;
        const float* br = Wm + (size_t)ncol * KD_ + K_;
        f32x16 acc = ZERO16;
#pragma unroll
        for (int kk = 0; kk < 4; kk++) {
            bf16x8 a = ldcvt8(ar + kk * 16 + dk);
            bf16x8 b = ldcvt8(br + kk * 16 + dk);
            acc = __builtin_amdgcn_mfma_f32_32x32x16_bf16(a, b, acc, 0, 0, 0);
        }
        const int nl_ = (w >> 1) * 32 + (l & 31);
#pragma unroll
        for (int r = 0; r < 16; r++) {
            const int row = (r & 3) + 8 * (r >> 2) + 4 * (l >> 5);
            shm[nl_ * 65 + (w & 1) * 32 + row] = fexp2(-LOG2E * acc[r]);
        }
        __syncthreads();
        float* Fo = mat ? FT2 : FT1;
#pragma unroll
        for (int i = 0; i < 16; i++) {
            const int q = i * 256 + t;
            const int r_ = q >> 6, c_ = q & 63;
            Fo[(size_t)(n0 + r_) * K_ + k0 + c_] = shm[r_ * 65 + c_];
        }
    }
}

// ---------------------------------------------------------------------------
// kMain v4: grid (2 kg, 32 bG, 8 ns) = 512 blocks, 512 thr (8 waves).
// Lane owns 4 k (float4 FT loads from L2) x 4 b (one b128 e-broadcast).
// Wave = (bh = w&1 [4 b], nq = w>>1 [16 n]); block = 256k x 8b x 64n.
// Per nl: 2 global float4 + 2 LDS b128 for 16 pairs (0.125 LDS instr/pair).
// w3: wave-uniform s_load. 2-way rcp batching (trans pipe halved).
// Cross-wave nq-reduce via conflict-free b32 component park. NO atomics.
// ---------------------------------------------------------------------------
__global__ void __launch_bounds__(512) kMain(const float* __restrict__ FT1,
                                             const float* __restrict__ FT2,
                                             const float* __restrict__ Ebase,
                                             const float* __restrict__ W3,
                                             float* __restrict__ pPart) {
    __shared__ float es[2][64][8];        // 4 KB
    __shared__ float sacc[3][2][16][64];  // 24 KB
    const int t = threadIdx.x, l = t & 63, w = t >> 6;
    const int kg = blockIdx.x, bG = blockIdx.y, ns = blockIdx.z;
    const int b0 = bG * 8, n0 = ns * 64;
    const int k = kg * 256 + l * 4;
    const int bh = w & 1, nq = w >> 1;

    // es[mat][n][b] = E[mat][b0+b][n0+n]; coalesced reads, strided LDS write
#pragma unroll
    for (int it = 0; it < 2; it++) {
        const int i = it * 512 + t;
        const int n = i & 63, b = (i >> 6) & 7, mat = i >> 9;
        es[mat][n][b] = Ebase[(size_t)mat * B_ * K_ + (size_t)(b0 + b) * K_ + n0 + n];
    }
    __syncthreads();

    const float* f1p = FT1 + (size_t)(n0 + nq * 16) * K_ + k;
    const float* f2p = FT2 + (size_t)(n0 + nq * 16) * K_ + k;
    const float* w3p = W3 + n0 + nq * 16;

    v4f acc[4];
#pragma unroll
    for (int b = 0; b < 4; b++) acc[b] = (v4f){0.f, 0.f, 0.f, 0.f};

#pragma unroll 4
    for (int nl = 0; nl < 16; nl++) {
        const v4f f1 = *(const v4f*)(f1p + (size_t)nl * K_);
        const v4f f2 = *(const v4f*)(f2p + (size_t)nl * K_);
        const float w3n = w3p[nl];                       // wave-uniform (s_load)
        const v4f e1 = *(const v4f*)&es[0][nq * 16 + nl][bh * 4];  // broadcast
        const v4f e2 = *(const v4f*)&es[1][nq * 16 + nl][bh * 4];
#pragma unroll
        for (int b = 0; b < 4; b++) {
            const v4f pd = e1[b] * f1 + 1.0f;
            const v4f qd = e2[b] * f2 + 1.0f;
            const v4f den = pd * qd;
            const v4f num = (qd - pd) * w3n;
            const float dxy = den.x * den.y, dzw = den.z * den.w;
            const float rxy = frcp(dxy), rzw = frcp(dzw);
            v4f rc;
            rc.x = rxy * den.y; rc.y = rxy * den.x;
            rc.z = rzw * den.w; rc.w = rzw * den.z;
            acc[b] += num * rc;
        }
    }

    // cross-wave reduce over nq (component-split b32 park: conflict-free)
    if (nq != 0) {
#pragma unroll
        for (int b = 0; b < 4; b++)
#pragma unroll
            for (int c = 0; c < 4; c++)
                sacc[nq - 1][bh][b * 4 + c][l] = acc[b][c];
    }
    __syncthreads();
    if (nq == 0) {
#pragma unroll
        for (int b = 0; b < 4; b++) {
            v4f s = acc[b];
#pragma unroll
            for (int q = 0; q < 3; q++) {
                s.x += sacc[q][bh][b * 4 + 0][l];
                s.y += sacc[q][bh][b * 4 + 1][l];
                s.z += sacc[q][bh][b * 4 + 2][l];
                s.w += sacc[q][bh][b * 4 + 3][l];
            }
            *(v4f*)(pPart + ((size_t)ns * B_ + b0 + bh * 4 + b) * K_ + k) = s;
        }
    }
}

// ---------------------------------------------------------------------------
// kFin (64 blocks x 256): wave w -> b = bid*4 + w.
// out[b] = sum_k sigmoid(sum_{ns<8} pPart + b3) * kn_emb[b,k] / sum_n kn_emb
// ---------------------------------------------------------------------------
__global__ void __launch_bounds__(256) kFin(const float* __restrict__ pPart,
                                            const float* __restrict__ kn_emb,
                                            const float* __restrict__ b3,
                                            float* __restrict__ out) {
    const int t = threadIdx.x, l = t & 63, w = t >> 6;
    const int b = blockIdx.x * 4 + w;
    const float b3v = b3[0];
    const float* ke = kn_emb + (size_t)b * K_;
    float num = 0.f, den = 0.f;
#pragma unroll
    for (int c = 0; c < 8; c++) {
        const int kk = c * 64 + l;
        float sv = 0.f;
#pragma unroll
        for (int s = 0; s < 8; s++)
            sv += pPart[((size_t)s * B_ + b) * K_ + kk];
        const float kv = ke[kk];
        num = fmaf(fsig(sv + b3v), kv, num);
        den += kv;
    }
#pragma unroll
    for (int off = 32; off; off >>= 1) {
        num += __shfl_xor(num, off, 64);
        den += __shfl_xor(den, off, 64);
    }
    if (l == 0) out[b] = num / den;
}

extern "C" void kernel_launch(void* const* d_in, const int* in_sizes, int n_in,
                              void* d_out, int out_size, void* d_ws, size_t ws_size,
                              hipStream_t stream) {
    const int*   stu_id     = (const int*)d_in[0];
    const int*   exer_id    = (const int*)d_in[1];
    const float* kn_emb     = (const float*)d_in[2];
    const float* stu_table  = (const float*)d_in[3];
    const float* exer_table = (const float*)d_in[4];
    const float* kn_table   = (const float*)d_in[5];
    const float* W1         = (const float*)d_in[6];
    const float* W2         = (const float*)d_in[7];
    const float* W3         = (const float*)d_in[8];
    const float* b3         = (const float*)d_in[9];
    float* out = (float*)d_out;

    float* ws = (float*)d_ws;
    float* FT1   = ws;                                 // K*K f
    float* FT2   = FT1 + (size_t)K_ * K_;              // K*K f
    float* E     = FT2 + (size_t)K_ * K_;              // 2*B*K f
    ushort* Sbu  = (ushort*)(E + 2 * (size_t)B_ * K_); // 2*B*K ushorts
    float* pPart = (float*)(Sbu + 2 * (size_t)B_ * K_);// 8*B*K f = 4 MB

    kS<<<64, 256, 0, stream>>>(stu_id, exer_id, stu_table, exer_table,
                               kn_table, Sbu);
    kEF<<<384, 256, 0, stream>>>(Sbu, W1, W2, kn_table, E, FT1, FT2);
    kMain<<<dim3(2, 32, 8), 512, 0, stream>>>(FT1, FT2, E, W3, pPart);
    kFin<<<64, 256, 0, stream>>>(pPart, kn_emb, b3, out);
}